// Round 4
// baseline (641.425 us; speedup 1.0000x reference)
//
#include <hip/hip_runtime.h>

// Problem constants (B,T,HID)=(4,2048,2048), heads 16, kv 2, hd 128.
#define B_    4
#define T_    2048
#define HID_  2048
#define NH_   16
#define NKV_  2
#define HD_   128
#define M_    (B_ * T_)      // 8192 rows
#define NQKV_ 2560           // 16*128 + 2*128 + 2*128

typedef __bf16 bf16x8 __attribute__((ext_vector_type(8)));
typedef float  f32x4  __attribute__((ext_vector_type(4)));

#define AS1 __attribute__((address_space(1)))
#define AS3 __attribute__((address_space(3)))

#if __has_builtin(__builtin_amdgcn_exp2f)
#define EXP2(x) __builtin_amdgcn_exp2f(x)
#else
#define EXP2(x) exp2f(x)
#endif

// async global->LDS, 16B per lane; LDS dest = wave-uniform base + lane*16
__device__ __forceinline__ void load_lds16(const void* g, void* l) {
  __builtin_amdgcn_global_load_lds((const AS1 unsigned int*)g,
                                   (AS3 unsigned int*)l, 16, 0, 0);
}

__device__ __forceinline__ unsigned short f2bf(float x) {
  union { float f; unsigned u; } a; a.f = x;
  unsigned r = a.u + 0x7fffu + ((a.u >> 16) & 1u);   // RNE
  return (unsigned short)(r >> 16);
}
__device__ __forceinline__ float bf2f(unsigned h) {
  union { unsigned u; float f; } a; a.u = h << 16;
  return a.f;
}
// pack two fp32 -> u32 of two bf16 (RTZ; P in [0,1], bias negligible)
__device__ __forceinline__ unsigned pk_rtz(float lo, float hi) {
  union { float f; unsigned u; } a, b; a.f = lo; b.f = hi;
  return (a.u >> 16) | (b.u & 0xffff0000u);
}

// ---------------- cast f32 -> bf16 (4 elems/thread) ----------------
__global__ __launch_bounds__(256) void cast_bf16(const float* __restrict__ in,
                                                 unsigned short* __restrict__ out,
                                                 int n4) {
  int i = blockIdx.x * 256 + threadIdx.x;
  if (i >= n4) return;
  float4 v = ((const float4*)in)[i];
  ushort4 o;
  o.x = f2bf(v.x); o.y = f2bf(v.y); o.z = f2bf(v.z); o.w = f2bf(v.w);
  ((ushort4*)out)[i] = o;
}

// merged Wq|Wk|Wv cast into contiguous wqkv (dest float4-index == i)
__global__ __launch_bounds__(256) void cast_w(const float* __restrict__ Wq,
                                              const float* __restrict__ Wk,
                                              const float* __restrict__ Wv,
                                              unsigned short* __restrict__ out) {
  int i = blockIdx.x * 256 + threadIdx.x;  // 5120*256 = 1310720 exact
  const float* src; int j;
  if (i < 1048576)      { src = Wq; j = i; }
  else if (i < 1179648) { src = Wk; j = i - 1048576; }
  else                  { src = Wv; j = i - 1179648; }
  float4 v = ((const float4*)src)[j];
  ushort4 o;
  o.x = f2bf(v.x); o.y = f2bf(v.y); o.z = f2bf(v.z); o.w = f2bf(v.w);
  ((ushort4*)out)[i] = o;
}

// ---------------- GEMM C = A * B^T (A: MxK row-major bf16, B: NxK row-major bf16)
// m97-style + 16B-unit XOR swizzle by (row>>1)&3 to kill fragment-read bank conflicts.
template <int OUT_BF16>
__global__ __launch_bounds__(256) void gemm_bt(const unsigned short* __restrict__ A,
                                               const unsigned short* __restrict__ Bm,
                                               void* __restrict__ C,
                                               int M, int N, int K) {
  __shared__ __align__(16) unsigned short As[128 * 32];
  __shared__ __align__(16) unsigned short Bs[128 * 32];
  const int tid = threadIdx.x;
  const int w = tid >> 6, lane = tid & 63;
  const int m0 = blockIdx.y << 7, n0 = blockIdx.x << 7;
  const int c = lane & 15, grp = lane >> 4;
  const int lr = lane >> 2;
  const int su = (((lane & 3) ^ ((lr >> 1) & 3)) << 3);   // staging source unit (swizzled)
  const int sw = (c >> 1) & 3;                            // read-side swizzle key
  const int wm = (w & 1) << 6, wn = (w >> 1) << 6;
  f32x4 acc[4][4] = {};
  for (int k0 = 0; k0 < K; k0 += 32) {
    __syncthreads();
    {
      int r0 = w << 4;
      load_lds16(A + (size_t)(m0 + r0 + lr) * K + k0 + su, &As[r0 * 32]);
      load_lds16(A + (size_t)(m0 + 64 + r0 + lr) * K + k0 + su, &As[(64 + r0) * 32]);
      load_lds16(Bm + (size_t)(n0 + r0 + lr) * K + k0 + su, &Bs[r0 * 32]);
      load_lds16(Bm + (size_t)(n0 + 64 + r0 + lr) * K + k0 + su, &Bs[(64 + r0) * 32]);
    }
    __syncthreads();
    bf16x8 af[4], bf[4];
#pragma unroll
    for (int i = 0; i < 4; i++)
      af[i] = *(const bf16x8*)&As[(wm + i * 16 + c) * 32 + ((grp ^ sw) << 3)];
#pragma unroll
    for (int j = 0; j < 4; j++)
      bf[j] = *(const bf16x8*)&Bs[(wn + j * 16 + c) * 32 + ((grp ^ sw) << 3)];
#pragma unroll
    for (int i = 0; i < 4; i++)
#pragma unroll
      for (int j = 0; j < 4; j++)
        acc[i][j] = __builtin_amdgcn_mfma_f32_16x16x32_bf16(af[i], bf[j], acc[i][j], 0, 0, 0);
  }
#pragma unroll
  for (int i = 0; i < 4; i++)
#pragma unroll
    for (int j = 0; j < 4; j++)
#pragma unroll
      for (int r = 0; r < 4; r++) {
        int row = m0 + wm + i * 16 + grp * 4 + r;
        int col = n0 + wn + j * 16 + c;
        float v = acc[i][j][r];
        if (OUT_BF16) ((unsigned short*)C)[(size_t)row * N + col] = f2bf(v);
        else          ((float*)C)[(size_t)row * N + col] = v;
      }
}

// ---------------- RoPE + RMSNorm. One wave per head per (b,t).
// q additionally pre-scaled by attn_scale*log2(e) so flash's softmax uses exp2 directly.
__global__ __launch_bounds__(256) void rope_norm(const unsigned short* __restrict__ qkv,
                                                 const float* __restrict__ cosb,
                                                 const float* __restrict__ sinb,
                                                 unsigned short* __restrict__ qo,
                                                 unsigned short* __restrict__ ko,
                                                 unsigned short* __restrict__ vo) {
  const int m = blockIdx.x;
  const int b = m >> 11, t = m & 2047;
  const int w = threadIdx.x >> 6, lane = threadIdx.x & 63;
  const float cv = cosb[t * 64 + lane], sv = sinb[t * 64 + lane];
  const unsigned short* row = qkv + (size_t)m * NQKV_;
  const float QSCL = 0.08838834764831845f * 1.4426950408889634f;  // 1/sqrt(128)*log2(e)
  for (int hh = w; hh < 20; hh += 4) {
    if (hh < 18) {
      const int col0 = (hh < 16) ? hh * 128 : 2048 + (hh - 16) * 128;
      unsigned pr = *(const unsigned*)(row + col0 + 2 * lane);
      float xr = bf2f(pr & 0xffffu), xi = bf2f(pr >> 16);
      float orr = xr * cv - xi * sv;
      float oi  = xr * sv + xi * cv;
      float ss = orr * orr + oi * oi;
#pragma unroll
      for (int off = 1; off < 64; off <<= 1) ss += __shfl_xor(ss, off);
      float scl = rsqrtf(ss * (1.0f / 128.0f) + 1.1920929e-07f);  // fp32 eps
      if (hh < 16) {
        float s2 = scl * QSCL;
        unsigned out = (unsigned)f2bf(orr * s2) | ((unsigned)f2bf(oi * s2) << 16);
        *(unsigned*)(qo + (((size_t)(b * NH_ + hh)) * T_ + t) * HD_ + 2 * lane) = out;
      } else {
        unsigned out = (unsigned)f2bf(orr * scl) | ((unsigned)f2bf(oi * scl) << 16);
        *(unsigned*)(ko + (((size_t)(b * NKV_ + (hh - 16))) * T_ + t) * HD_ + 2 * lane) = out;
      }
    } else {
      const int gg = hh - 18;
      unsigned pr = *(const unsigned*)(row + 2304 + gg * 128 + 2 * lane);
      *(unsigned*)(vo + (((size_t)(b * NKV_ + gg)) * T_ + t) * HD_ + 2 * lane) = pr;
    }
  }
}

// ---------------- V transpose: (bg, T, HD) -> (bg, HD, T), 64x64 LDS tiles.
// Output columns are PERMUTED within each 32-kv chunk so flash's PV A-fragment
// is one contiguous b128: position p=8g+4a+b holds kv=16a+4g+b.
__global__ __launch_bounds__(256) void transpose_v(const unsigned short* __restrict__ v,
                                                   unsigned short* __restrict__ vt) {
  __shared__ unsigned short tile[64][65];
  const int bg = blockIdx.z;
  const int t0 = blockIdx.x << 6, h0 = blockIdx.y << 6;
  const unsigned short* src = v + (size_t)bg * T_ * HD_;
  unsigned short* dst = vt + (size_t)bg * T_ * HD_;
  const int tid = threadIdx.x;
  const int rr = tid >> 4, cc = (tid & 15) << 2;
  const int u = (cc >> 2) & 7;
  const int cp = (cc & 32) + 16 * (u & 1) + 4 * ((u >> 1) & 3);  // source col for dst col cc
#pragma unroll
  for (int it = 0; it < 4; it++) {
    int r = rr + it * 16;
    ushort4 d = *(const ushort4*)(src + (size_t)(t0 + r) * HD_ + h0 + cc);
    tile[r][cc + 0] = d.x; tile[r][cc + 1] = d.y;
    tile[r][cc + 2] = d.z; tile[r][cc + 3] = d.w;
  }
  __syncthreads();
#pragma unroll
  for (int it = 0; it < 4; it++) {
    int r = rr + it * 16;
    ushort4 d;
    d.x = tile[cp + 0][r]; d.y = tile[cp + 1][r];
    d.z = tile[cp + 2][r]; d.w = tile[cp + 3][r];
    *(ushort4*)(dst + (size_t)(h0 + r) * T_ + t0 + cc) = d;
  }
}

// ---------------- Flash attention v4: 512-thread blocks, 8 waves, each wave an
// independent 32-q strip. Block j takes strips {4j..4j+3} u {60-4j..63-4j} so
// every block has identical causal work (all 512 blocks co-resident, 16 waves/CU).
// S^T form, lane-local P, double-buffered 64-kv chunks, XOR-swizzled K/V LDS.
__global__ __launch_bounds__(512, 4) void flash_attn(const unsigned short* __restrict__ q,
                                                     const unsigned short* __restrict__ k,
                                                     const unsigned short* __restrict__ vt,
                                                     unsigned short* __restrict__ y) {
  __shared__ __align__(16) unsigned short Kb[2][8192];  // [buf][dc4][kv64][d-unit swz]
  __shared__ __align__(16) unsigned short Vb[2][8192];  // [buf][ks2][h128][kv-unit swz]
  const int tid = threadIdx.x;
  const int w = tid >> 6, lane = tid & 63;
  const int c = lane & 15, grp = lane >> 4;
  const int lr = lane >> 2;
  const int sw = (c >> 1) & 3;
  const int su = (((lane & 3) ^ ((lr >> 1) & 3)) << 3);
  const int j = blockIdx.x;                       // 0..7
  const int sigma = (w < 4) ? (4 * j + w) : (60 - 4 * j + (w - 4));
  const int qs = sigma << 5;                      // this wave's 32-q strip base
  const int hq = blockIdx.y, b = blockIdx.z, g = hq >> 3;
  const unsigned short* qbase = q + (((size_t)(b * NH_ + hq)) * T_ + qs) * HD_;
  const unsigned short* kbase = k + ((size_t)(b * NKV_ + g)) * T_ * HD_;
  const unsigned short* vtbase = vt + ((size_t)(b * NKV_ + g)) * HD_ * T_;

  // Q fragments (pre-scaled by scale*log2e): B-operand layout, rows q
  bf16x8 qf[2][4];
#pragma unroll
  for (int ti = 0; ti < 2; ti++)
#pragma unroll
    for (int ks = 0; ks < 4; ks++)
      qf[ti][ks] = *(const bf16x8*)(qbase + (size_t)(ti * 16 + c) * HD_ + ks * 32 + grp * 8);

  f32x4 oacc[2][8] = {};            // O^T: row h=hj*16+grp*4+r, col q=ti*16+c
  float mrun[2], lrun[2];
  mrun[0] = mrun[1] = -__builtin_inff();
  lrun[0] = lrun[1] = 0.f;

  // staging split over 8 waves: 2 K-segments + 2 V-segments (1 KB each) per wave
  const int kdc = w >> 1, krb = (w & 1) << 5;     // K: d-chunk, kv row-block
  const int vks = (w >> 2) & 1, vrb = (w & 3) << 5;  // V: kv-chunk, h row-block
  auto stage = [&](int s0, int bb) {
    load_lds16(kbase + (size_t)(s0 + krb + lr) * HD_ + kdc * 32 + su,
               &Kb[bb][kdc * 2048 + krb * 32]);
    load_lds16(kbase + (size_t)(s0 + krb + 16 + lr) * HD_ + kdc * 32 + su,
               &Kb[bb][kdc * 2048 + (krb + 16) * 32]);
    load_lds16(vtbase + (size_t)(vrb + lr) * T_ + s0 + vks * 32 + su,
               &Vb[bb][vks * 4096 + vrb * 32]);
    load_lds16(vtbase + (size_t)(vrb + 16 + lr) * T_ + s0 + vks * 32 + su,
               &Vb[bb][vks * 4096 + (vrb + 16) * 32]);
  };

  const int nch = 32 - 2 * j;       // chunks needed for this block's max strip (63-4j)
  stage(0, 0);
  __syncthreads();                  // chunk 0 resident
  for (int ic = 0; ic < nch; ic++) {
    const int s0 = ic << 6, bb = ic & 1;
    if (ic + 1 < nch) stage((ic + 1) << 6, bb ^ 1);   // async prefetch, drained at loop-end barrier
    if (s0 <= qs + 31) {            // wave has unmasked work in this chunk
      const unsigned short* Kc = Kb[bb];
      const unsigned short* Vc = Vb[bb];
      // S^T = K·Q^T : lane holds P[q=ti*16+c][kv=kvt*16+grp*4+r] (log2 domain)
      f32x4 st[2][4] = {};
#pragma unroll
      for (int s = 0; s < 4; s++)
#pragma unroll
        for (int kvt = 0; kvt < 4; kvt++) {
          bf16x8 ak = *(const bf16x8*)&Kc[s * 2048 + (kvt * 16 + c) * 32 + ((grp ^ sw) << 3)];
          st[0][kvt] = __builtin_amdgcn_mfma_f32_16x16x32_bf16(ak, qf[0][s], st[0][kvt], 0, 0, 0);
          st[1][kvt] = __builtin_amdgcn_mfma_f32_16x16x32_bf16(ak, qf[1][s], st[1][kvt], 0, 0, 0);
        }
      if (s0 + 63 > qs) {           // diagonal chunk: causal mask
#pragma unroll
        for (int ti = 0; ti < 2; ti++)
#pragma unroll
          for (int kvt = 0; kvt < 4; kvt++)
#pragma unroll
            for (int r = 0; r < 4; r++) {
              int kv = s0 + kvt * 16 + grp * 4 + r;
              int qq = qs + ti * 16 + c;
              if (kv > qq) st[ti][kvt][r] = -__builtin_inff();
            }
      }
      // online softmax per q-column (lane-local + cross-grp butterfly)
      unsigned pkv[2][4][2];
#pragma unroll
      for (int ti = 0; ti < 2; ti++) {
        float rm = st[ti][0][0];
#pragma unroll
        for (int kvt = 0; kvt < 4; kvt++)
#pragma unroll
          for (int r = 0; r < 4; r++) rm = fmaxf(rm, st[ti][kvt][r]);
        rm = fmaxf(rm, __shfl_xor(rm, 16));
        rm = fmaxf(rm, __shfl_xor(rm, 32));
        float mnew = fmaxf(mrun[ti], rm);
        float alpha = EXP2(mrun[ti] - mnew);
        mrun[ti] = mnew;
        float rs = 0.f;
#pragma unroll
        for (int kvt = 0; kvt < 4; kvt++) {
          float p0 = EXP2(st[ti][kvt][0] - mnew);
          float p1 = EXP2(st[ti][kvt][1] - mnew);
          float p2 = EXP2(st[ti][kvt][2] - mnew);
          float p3 = EXP2(st[ti][kvt][3] - mnew);
          rs += (p0 + p1) + (p2 + p3);
          pkv[ti][kvt][0] = pk_rtz(p0, p1);
          pkv[ti][kvt][1] = pk_rtz(p2, p3);
        }
        rs += __shfl_xor(rs, 16);
        rs += __shfl_xor(rs, 32);
        lrun[ti] = lrun[ti] * alpha + rs;
#pragma unroll
        for (int hj = 0; hj < 8; hj++)
#pragma unroll
          for (int r = 0; r < 4; r++) oacc[ti][hj][r] *= alpha;
      }
      // O^T += V^T·P (k permuted; V pre-permuted so A-frag is one b128)
#pragma unroll
      for (int s = 0; s < 2; s++) {
        union { int4 i; bf16x8 v; } pf0, pf1;
        pf0.i = make_int4(pkv[0][2 * s][0], pkv[0][2 * s][1], pkv[0][2 * s + 1][0], pkv[0][2 * s + 1][1]);
        pf1.i = make_int4(pkv[1][2 * s][0], pkv[1][2 * s][1], pkv[1][2 * s + 1][0], pkv[1][2 * s + 1][1]);
#pragma unroll
        for (int hj = 0; hj < 8; hj++) {
          union { int4 i; bf16x8 v; } av;
          av.i = *(const int4*)&Vc[s * 4096 + (hj * 16 + c) * 32 + ((grp ^ sw) << 3)];
          oacc[0][hj] = __builtin_amdgcn_mfma_f32_16x16x32_bf16(av.v, pf0.v, oacc[0][hj], 0, 0, 0);
          oacc[1][hj] = __builtin_amdgcn_mfma_f32_16x16x32_bf16(av.v, pf1.v, oacc[1][hj], 0, 0, 0);
        }
      }
    }
    __syncthreads();   // drains prefetch (issued a full compute ago) + buffer handoff
  }

  // epilogue: lane owns O^T[h][q=ti*16+c]; l is lane-local.
#pragma unroll
  for (int ti = 0; ti < 2; ti++) {
    float inv = 1.f / lrun[ti];
    int trow = qs + ti * 16 + c;
#pragma unroll
    for (int hj = 0; hj < 8; hj++) {
      ushort4 o;
      o.x = f2bf(oacc[ti][hj][0] * inv);
      o.y = f2bf(oacc[ti][hj][1] * inv);
      o.z = f2bf(oacc[ti][hj][2] * inv);
      o.w = f2bf(oacc[ti][hj][3] * inv);
      *(ushort4*)&y[((size_t)(b * T_ + trow)) * HID_ + hq * HD_ + hj * 16 + grp * 4] = o;
    }
  }
}

// ---------------- launcher ----------------
extern "C" void kernel_launch(void* const* d_in, const int* in_sizes, int n_in,
                              void* d_out, int out_size, void* d_ws, size_t ws_size,
                              hipStream_t stream) {
  const float* x    = (const float*)d_in[0];
  const float* cosb = (const float*)d_in[1];
  const float* sinb = (const float*)d_in[2];
  const float* Wq   = (const float*)d_in[3];
  const float* Wk   = (const float*)d_in[4];
  const float* Wv   = (const float*)d_in[5];
  const float* Wo   = (const float*)d_in[6];
  float* out = (float*)d_out;

  char* ws = (char*)d_ws;
  size_t off = 0;
  auto take = [&](size_t elems) {
    unsigned short* p = (unsigned short*)(ws + off);
    off += ((elems * 2 + 255) & ~(size_t)255);
    return p;
  };
  unsigned short* xb   = take((size_t)M_ * HID_);
  unsigned short* wqkv = take((size_t)NQKV_ * HID_);
  unsigned short* wob  = take((size_t)HID_ * HID_);
  unsigned short* qkv  = take((size_t)M_ * NQKV_);
  unsigned short* qb   = take((size_t)B_ * NH_ * T_ * HD_);
  unsigned short* kb   = take((size_t)B_ * NKV_ * T_ * HD_);
  unsigned short* vb   = take((size_t)B_ * NKV_ * T_ * HD_);
  unsigned short* vtb  = take((size_t)B_ * NKV_ * T_ * HD_);
  unsigned short* yb   = take((size_t)M_ * HID_);
  (void)ws_size; (void)in_sizes; (void)n_in; (void)out_size;

  cast_bf16<<<16384, 256, 0, stream>>>(x, xb, 4194304);
  cast_w<<<5120, 256, 0, stream>>>(Wq, Wk, Wv, wqkv);
  cast_bf16<<<4096, 256, 0, stream>>>(Wo, wob, 1048576);

  gemm_bt<1><<<dim3(20, 64), 256, 0, stream>>>(xb, wqkv, qkv, M_, NQKV_, HID_);
  rope_norm<<<8192, 256, 0, stream>>>(qkv, cosb, sinb, qb, kb, vb);
  transpose_v<<<dim3(32, 2, 8), 256, 0, stream>>>(vb, vtb);
  flash_attn<<<dim3(8, 16, 4), 512, 0, stream>>>(qb, kb, vtb, yb);
  gemm_bt<0><<<dim3(16, 64), 256, 0, stream>>>(yb, wob, out, M_, HID_, HID_);
}